// Round 6
// baseline (706.967 us; speedup 1.0000x reference)
//
#include <hip/hip_runtime.h>
#include <stdint.h>

// ---------------- constants ----------------
#define NPOS 2500      // 50*50
#define NANCH 22500    // NPOS*9
#define NPRE 6000
#define NW 94          // ceil(6000/64)
#define XPAD 2704      // 52*52 padded plane

// async global->LDS DMA (gfx950). dst is wave-uniform base + lane*size.
__device__ __forceinline__ void gl_lds4(const float* g, float* l) {
  __builtin_amdgcn_global_load_lds((const __attribute__((address_space(1))) void*)g,
                                   (__attribute__((address_space(3))) void*)l, 4, 0, 0);
}
__device__ __forceinline__ void gl_lds16(const float* g, float* l) {
  __builtin_amdgcn_global_load_lds((const __attribute__((address_space(1))) void*)g,
                                   (__attribute__((address_space(3))) void*)l, 16, 0, 0);
}

// ---------------- zero-pad x: [b][ic][50][50] -> [b][ic][52][52] ----------------
__global__ __launch_bounds__(256) void pad_x(const float* __restrict__ x,
                                             float* __restrict__ xp) {
  int t = blockIdx.x * 256 + threadIdx.x;
  if (t >= 2 * 256 * XPAD) return;
  int c = t / XPAD;        // b*256 + ic
  int r = t % XPAD;
  int yy = r / 52, xx = r % 52;
  float v = 0.f;
  if (yy >= 1 && yy <= 50 && xx >= 1 && xx <= 50)
    v = x[(size_t)c * NPOS + (yy - 1) * 50 + (xx - 1)];
  xp[t] = v;
}

// ---------------- weight transpose: w[oc][ic][3][3] -> wt[(tap*256+ic)][oc] ----------------
__global__ __launch_bounds__(256) void transpose_w(const float* __restrict__ w,
                                                   float* __restrict__ wt) {
  __shared__ float tile[32][33];
  int k0 = blockIdx.x * 32;   // k' = ic*9 + tap, 0..2303
  int o0 = blockIdx.y * 32;
  int tx = threadIdx.x & 31;
  int ty = threadIdx.x >> 5;  // 0..7
#pragma unroll
  for (int i = 0; i < 4; ++i) {
    int oc = o0 + ty + i * 8;
    int kp = k0 + tx;
    tile[ty + i * 8][tx] = w[(size_t)oc * 2304 + kp];
  }
  __syncthreads();
#pragma unroll
  for (int i = 0; i < 4; ++i) {
    int kp = k0 + ty + i * 8;
    int ic = kp / 9, tap = kp % 9;
    wt[((size_t)tap * 256 + ic) * 512 + (o0 + tx)] = tile[tx][ty + i * 8];
  }
}

// ---------------- conv1 3x3 SAME + bias + relu, output NHWC h[b][p][oc] ----------------
// R2's 64x64 tile / tap-outer ic-inner K-order (bitwise-identical h), staging via
// global_load_lds DMA from zero-padded xp. (R5: 253 -> ~180us, left top-5.)
__global__ __launch_bounds__(256) void conv1_gemm(const float* __restrict__ xp,
                                                  const float* __restrict__ wt,
                                                  const float* __restrict__ bias,
                                                  float* __restrict__ h) {
  __shared__ __align__(16) float As[32][64];
  __shared__ __align__(16) float Bs[32][64];
  int b = blockIdx.z;
  int m0 = blockIdx.x * 64;
  int oc0 = blockIdx.y * 64;
  int tid = threadIdx.x;
  int lane = tid & 63;
  int wv = tid >> 6;       // wave 0..3
  int tn = tid & 15, tm = tid >> 4;
  float acc[4][4] = {};

  int p = m0 + lane;
  int pc = p < NPOS ? p : (NPOS - 1);
  int py = pc / 50, px = pc % 50;
  const float* gA0 = xp + (size_t)b * 256 * XPAD + py * 52 + px + 53;
  int brow = lane >> 4, bcol4 = (lane & 15) * 4;

  for (int tap = 0; tap < 9; ++tap) {
    int ky = tap / 3 - 1, kx = tap % 3 - 1;
    int koff = ky * 52 + kx;
    for (int icc = 0; icc < 8; ++icc) {
      int ic0 = icc * 32;
      __syncthreads();  // LDS consumed by previous chunk's compute
#pragma unroll
      for (int j = 0; j < 8; ++j) {
        int kk = wv * 8 + j;
        gl_lds4(gA0 + (size_t)(ic0 + kk) * XPAD + koff, &As[kk][0]);
      }
#pragma unroll
      for (int q = 0; q < 2; ++q) {
        int r0 = wv * 8 + q * 4;
        gl_lds16(wt + ((size_t)tap * 256 + ic0 + r0 + brow) * 512 + oc0 + bcol4,
                 &Bs[r0][0]);
      }
      __syncthreads();  // drains vmcnt -> DMAs complete
#pragma unroll
      for (int kk = 0; kk < 32; ++kk) {
        float4 av = *(const float4*)&As[kk][tm * 4];
        float4 bv = *(const float4*)&Bs[kk][tn * 4];
        float am[4] = {av.x, av.y, av.z, av.w};
        float bn[4] = {bv.x, bv.y, bv.z, bv.w};
#pragma unroll
        for (int i = 0; i < 4; ++i)
#pragma unroll
          for (int j = 0; j < 4; ++j) acc[i][j] = fmaf(am[i], bn[j], acc[i][j]);
      }
    }
  }
#pragma unroll
  for (int i = 0; i < 4; ++i) {
    int pp = m0 + tm * 4 + i;
    if (pp < NPOS) {
      float4 v;
      float* vp = (float*)&v;
#pragma unroll
      for (int j = 0; j < 4; ++j) {
        int oc = oc0 + tn * 4 + j;
        vp[j] = fmaxf(acc[i][j] + bias[oc], 0.f);
      }
      *(float4*)&h[((size_t)b * NPOS + pp) * 512 + oc0 + tn * 4] = v;
    }
  }
}

// ---------------- heads: 1x1 convs + softmax + decode + valid ----------------
__global__ __launch_bounds__(64) void heads(const float* __restrict__ h,
                                            const float* __restrict__ objw,
                                            const float* __restrict__ objb,
                                            const float* __restrict__ locw,
                                            const float* __restrict__ locb,
                                            const float* __restrict__ anch,
                                            const int* __restrict__ imgh,
                                            const int* __restrict__ imgw,
                                            float* __restrict__ scores,
                                            float4* __restrict__ boxes) {
  __shared__ float hv[512];
  __shared__ float outs[64];
  int blk = blockIdx.x;
  int b = blk / NPOS, p = blk % NPOS;
  int lane = threadIdx.x;
  const float4* hp4 = (const float4*)(h + ((size_t)b * NPOS + p) * 512);
  float4* hv4 = (float4*)hv;
  hv4[lane] = hp4[lane];
  hv4[lane + 64] = hp4[lane + 64];
  __syncthreads();
  if (lane < 54) {
    const float* wrow;
    float acc;
    if (lane < 18) { wrow = objw + (size_t)lane * 512; acc = objb[lane]; }
    else           { wrow = locw + (size_t)(lane - 18) * 512; acc = locb[lane - 18]; }
    const float4* w4 = (const float4*)wrow;
#pragma unroll 4
    for (int k = 0; k < 128; ++k) {
      float4 wv = w4[k], hh = hv4[k];
      acc = fmaf(wv.x, hh.x, acc);
      acc = fmaf(wv.y, hh.y, acc);
      acc = fmaf(wv.z, hh.z, acc);
      acc = fmaf(wv.w, hh.w, acc);
    }
    outs[lane] = acc;
  }
  __syncthreads();
  if (lane < 9) {
    float l0 = outs[2 * lane], l1 = outs[2 * lane + 1];
    float mx = fmaxf(l0, l1);
    float e0 = expf(l0 - mx);
    float e1 = expf(l1 - mx);
    float s = e1 / (e0 + e1);
    float d0 = outs[18 + 4 * lane + 0];
    float d1 = outs[18 + 4 * lane + 1];
    float d2 = outs[18 + 4 * lane + 2];
    float d3 = outs[18 + 4 * lane + 3];
    int ai = p * 9 + lane;
    float4 A = ((const float4*)anch)[ai];
    float aw = A.z - A.x, ah = A.w - A.y;
    float acx = A.x + 0.5f * aw, acy = A.y + 0.5f * ah;
    float cx = acx + d0 * aw, cy = acy + d1 * ah;
    float w = aw * expf(d2), hh = ah * expf(d3);
    float W = (float)imgw[0], H = (float)imgh[0];
    float x1 = fminf(fmaxf(cx - 0.5f * w, 0.f), W);
    float y1 = fminf(fmaxf(cy - 0.5f * hh, 0.f), H);
    float x2 = fminf(fmaxf(cx + 0.5f * w, 0.f), W);
    float y2 = fminf(fmaxf(cy + 0.5f * hh, 0.f), H);
    bool valid = (x2 - x1 >= 16.f) && (y2 - y1 >= 16.f);
    scores[(size_t)b * NANCH + ai] = valid ? s : -1.f;
    boxes[(size_t)b * NANCH + ai] = make_float4(x1, y1, x2, y2);
  }
}

// ---------------- top-6000 select + sort (one block per batch) ----------------
__device__ inline unsigned int mono_of(float f) {
  unsigned int u = __float_as_uint(f);
  return (u & 0x80000000u) ? ~u : (u | 0x80000000u);
}

// Wave-aggregated histogram add: one LDS atomic per distinct bin per wave.
// R5 counters: scores cluster (~0.5 +- 0.005) -> plain per-lane atomics serialize
// (SQ_LDS_BANK_CONFLICT ~= NANCH, topk 201us at 0.4% VALUBusy).
__device__ __forceinline__ void hist_add(unsigned int* hist, int bin, bool act) {
  int lane = threadIdx.x & 63;
  unsigned long long mask = __ballot(act);
  while (mask) {
    int leader = __ffsll((long long)mask) - 1;
    int lbin = __shfl(bin, leader, 64);
    unsigned long long eq = __ballot(act && (bin == lbin));
    if (lane == leader) atomicAdd(&hist[lbin], (unsigned int)__popcll(eq));
    mask &= ~eq;
  }
}

#define NITER ((NANCH + 1023) / 1024 * 1024)  // uniform trip count for ballot convergence

__global__ __launch_bounds__(1024) void topk_sort(const float* __restrict__ scores,
                                                  const float4* __restrict__ boxes,
                                                  float* __restrict__ sscore,
                                                  float4* __restrict__ sbox) {
  int b = blockIdx.x;
  const float* sc = scores + (size_t)b * NANCH;
  __shared__ unsigned int k32[8192];     // also used as histogram (first 4096)
  __shared__ unsigned short pidx[8192];
  __shared__ unsigned int part[1024];
  __shared__ int res[8];
  __shared__ int ctr;
  unsigned int* hist = k32;
  int tid = threadIdx.x;

  // ---------- phase 1: top-12-bit histogram ----------
  for (int i = tid; i < 4096; i += 1024) hist[i] = 0;
  __syncthreads();
  for (int i0 = 0; i0 < NITER; i0 += 1024) {
    int i = i0 + tid;
    bool act = i < NANCH;
    unsigned int m = act ? mono_of(sc[i]) : 0u;
    hist_add(hist, (int)(m >> 20), act);
  }
  __syncthreads();
  {
    unsigned int h0 = hist[4 * tid], h1 = hist[4 * tid + 1];
    unsigned int h2 = hist[4 * tid + 2], h3 = hist[4 * tid + 3];
    part[tid] = h0 + h1 + h2 + h3;
    __syncthreads();
    for (int off = 1; off < 1024; off <<= 1) {
      unsigned int v = part[tid];
      unsigned int u = (tid + off < 1024) ? part[tid + off] : 0;
      __syncthreads();
      part[tid] = v + u;
      __syncthreads();
    }
    unsigned int c = (tid < 1023) ? part[tid + 1] : 0;  // strict suffix over groups
    const int need = NPRE;
    if (c < (unsigned)need && c + h3 >= (unsigned)need) { res[0] = 4 * tid + 3; res[1] = (int)c; }
    c += h3;
    if (c < (unsigned)need && c + h2 >= (unsigned)need) { res[0] = 4 * tid + 2; res[1] = (int)c; }
    c += h2;
    if (c < (unsigned)need && c + h1 >= (unsigned)need) { res[0] = 4 * tid + 1; res[1] = (int)c; }
    c += h1;
    if (c < (unsigned)need && c + h0 >= (unsigned)need) { res[0] = 4 * tid + 0; res[1] = (int)c; }
  }
  __syncthreads();
  int t1 = res[0], a1 = res[1];
  __syncthreads();

  // ---------- phase 2: middle-12 bits within bin t1 ----------
  for (int i = tid; i < 4096; i += 1024) hist[i] = 0;
  __syncthreads();
  for (int i0 = 0; i0 < NITER; i0 += 1024) {
    int i = i0 + tid;
    bool act = i < NANCH;
    unsigned int m = act ? mono_of(sc[i]) : 0u;
    bool hit = act && ((int)(m >> 20) == t1);
    hist_add(hist, (int)((m >> 8) & 0xFFF), hit);
  }
  __syncthreads();
  {
    unsigned int h0 = hist[4 * tid], h1 = hist[4 * tid + 1];
    unsigned int h2 = hist[4 * tid + 2], h3 = hist[4 * tid + 3];
    part[tid] = h0 + h1 + h2 + h3;
    __syncthreads();
    for (int off = 1; off < 1024; off <<= 1) {
      unsigned int v = part[tid];
      unsigned int u = (tid + off < 1024) ? part[tid + off] : 0;
      __syncthreads();
      part[tid] = v + u;
      __syncthreads();
    }
    unsigned int c = (tid < 1023) ? part[tid + 1] : 0;
    const unsigned int need = (unsigned)(NPRE - a1);
    if (c < need && c + h3 >= need) { res[2] = 4 * tid + 3; res[3] = (int)c; }
    c += h3;
    if (c < need && c + h2 >= need) { res[2] = 4 * tid + 2; res[3] = (int)c; }
    c += h2;
    if (c < need && c + h1 >= need) { res[2] = 4 * tid + 1; res[3] = (int)c; }
    c += h1;
    if (c < need && c + h0 >= need) { res[2] = 4 * tid + 0; res[3] = (int)c; }
  }
  __syncthreads();
  int t2 = res[2], a2 = res[3];
  __syncthreads();

  // ---------- phase 3: low-8 bits within (t1,t2) ----------
  for (int i = tid; i < 256; i += 1024) hist[i] = 0;
  __syncthreads();
  unsigned int top24 = ((unsigned int)t1 << 12) | (unsigned int)t2;
  for (int i0 = 0; i0 < NITER; i0 += 1024) {
    int i = i0 + tid;
    bool act = i < NANCH;
    unsigned int m = act ? mono_of(sc[i]) : 0u;
    bool hit = act && ((m >> 8) == top24);
    hist_add(hist, (int)(m & 0xFF), hit);
  }
  __syncthreads();
  {
    unsigned int hb = (tid < 256) ? hist[tid] : 0;
    part[tid] = hb;
    __syncthreads();
    for (int off = 1; off < 1024; off <<= 1) {
      unsigned int v = part[tid];
      unsigned int u = (tid + off < 1024) ? part[tid + off] : 0;
      __syncthreads();
      part[tid] = v + u;
      __syncthreads();
    }
    if (tid < 256) {
      unsigned int c = part[tid + 1];
      const unsigned int need = (unsigned)(NPRE - a1 - a2);
      if (c < need && c + hb >= need) {
        res[4] = tid;
        res[6] = (int)(need - c);                         // ties_needed
        res[7] = (hb == need - c) ? NANCH : -1;           // idx_cut or TBD
      }
    }
  }
  __syncthreads();
  int t3 = res[4];
  unsigned int T = (top24 << 8) | (unsigned int)t3;
  int ties_needed = res[6];
  int idx_cut = res[7];
  __syncthreads();

  // ---------- phase 4 (rare): tie resolution by smallest index ----------
  if (idx_cut < 0) {
    for (int i = tid; i < 704; i += 1024) hist[i] = 0;
    __syncthreads();
    for (int i0 = 0; i0 < NITER; i0 += 1024) {
      int i = i0 + tid;
      bool act = i < NANCH;
      bool hit = act && (mono_of(sc[i]) == T);
      hist_add(hist, i >> 5, hit);
    }
    __syncthreads();
    if (tid == 0) {
      int c = 0, cut = NANCH;
      for (int bin = 0; bin < 704; ++bin) {
        int hc = (int)hist[bin];
        if (c + hc >= ties_needed) {
          int c2 = c;
          for (int idx = bin * 32; idx < bin * 32 + 32; ++idx) {
            if (idx < NANCH && mono_of(sc[idx]) == T) {
              ++c2;
              if (c2 == ties_needed) { cut = idx; break; }
            }
          }
          break;
        }
        c += hc;
      }
      res[7] = cut;
    }
    __syncthreads();
    idx_cut = res[7];
    __syncthreads();
  }

  // ---------- phase 5: compact exactly 6000 candidates (wave-aggregated counter) ----------
  for (int i = tid; i < 8192; i += 1024) { k32[i] = 0u; pidx[i] = 0xFFFFu; }
  if (tid == 0) ctr = 0;
  __syncthreads();
  for (int i0 = 0; i0 < NITER; i0 += 1024) {
    int i = i0 + tid;
    bool act = i < NANCH;
    unsigned int m = act ? mono_of(sc[i]) : 0u;
    bool sel = act && (m > T || (m == T && i <= idx_cut));
    unsigned long long bal = __ballot(sel);
    if (bal) {
      int lane = tid & 63;
      int leader = __ffsll((long long)bal) - 1;
      int wbase = 0;
      if (lane == leader) wbase = atomicAdd(&ctr, (int)__popcll(bal));
      wbase = __shfl(wbase, leader, 64);
      if (sel) {
        int pos = wbase + __popcll(bal & ((1ull << lane) - 1ull));
        k32[pos] = m;
        pidx[pos] = (unsigned short)i;
      }
    }
  }
  __syncthreads();

  // ---------- phase 6: bitonic sort descending (mono desc, idx asc), n=8192 ----------
  for (int kk = 2; kk <= 8192; kk <<= 1) {
    for (int j = kk >> 1; j > 0; j >>= 1) {
      for (int v = tid; v < 8192; v += 1024) {
        int q = v ^ j;
        if (q > v) {
          unsigned int ka = k32[v], kb = k32[q];
          unsigned short pa = pidx[v], pb = pidx[q];
          bool lt = (ka < kb) || (ka == kb && pa > pb);
          bool gt = (ka > kb) || (ka == kb && pa < pb);
          bool up = (v & kk) == 0;
          if (up ? lt : gt) { k32[v] = kb; k32[q] = ka; pidx[v] = pb; pidx[q] = pa; }
        }
      }
      __syncthreads();
    }
  }

  // ---------- phase 7: gather sorted scores/boxes ----------
  for (int r = tid; r < NPRE; r += 1024) {
    int idx = (int)pidx[r];
    sscore[(size_t)b * NPRE + r] = sc[idx];
    sbox[(size_t)b * NPRE + r] = boxes[(size_t)b * NANCH + idx];
  }
}

// ---------------- IoU suppression bitmask ----------------
__global__ __launch_bounds__(256) void iou_mat(const float4* __restrict__ sbox,
                                               uint64_t* __restrict__ M) {
  __shared__ float4 bi[64];
  __shared__ float4 bj[256];
  int b = blockIdx.z;
  int it = blockIdx.x;  // 94 tiles of 64 i
  int jt = blockIdx.y;  // 24 tiles of 4 words
  int tid = threadIdx.x;
  if (tid < 64) {
    int i = it * 64 + tid;
    bi[tid] = (i < NPRE) ? sbox[(size_t)b * NPRE + i] : make_float4(0, 0, 0, 0);
  }
  {
    int j = jt * 256 + tid;
    bj[tid] = (j < NPRE) ? sbox[(size_t)b * NPRE + j] : make_float4(0, 0, 0, 0);
  }
  __syncthreads();
  int li = tid & 63, wq = tid >> 6;
  int i = it * 64 + li;
  int w = jt * 4 + wq;
  if (i < NPRE && w < NW) {
    float4 A = bi[li];
    float areaA = (A.z - A.x) * (A.w - A.y);
    uint64_t bits = 0;
#pragma unroll 8
    for (int jj = 0; jj < 64; ++jj) {
      int j = w * 64 + jj;
      float4 Bx = bj[wq * 64 + jj];
      float ix1 = fmaxf(A.x, Bx.x), iy1 = fmaxf(A.y, Bx.y);
      float ix2 = fminf(A.z, Bx.z), iy2 = fminf(A.w, Bx.w);
      float inter = fmaxf(ix2 - ix1, 0.f) * fmaxf(iy2 - iy1, 0.f);
      float areaB = (Bx.z - Bx.x) * (Bx.w - Bx.y);
      float iou = inter / (areaA + areaB - inter);
      if ((j > i) && (j < NPRE) && (iou > 0.7f)) bits |= (1ull << jj);
    }
    M[((size_t)b * NPRE + i) * NW + w] = bits;
  }
}

// ---------------- NMS scan: wave0 serial closure + block-parallel OR + early exit ----------------
__device__ inline uint64_t shfl64(uint64_t v, int src) {
  int lo = __shfl((int)(unsigned int)(v & 0xFFFFFFFFull), src, 64);
  int hi = __shfl((int)(unsigned int)(v >> 32), src, 64);
  return ((uint64_t)(unsigned int)hi << 32) | (unsigned int)lo;
}

__global__ __launch_bounds__(1024) void nms_scan(const uint64_t* __restrict__ M,
                                                 const float* __restrict__ sscore,
                                                 uint64_t* __restrict__ keep) {
  __shared__ unsigned int supLo[NW], supHi[NW];
  __shared__ int klist[64];
  __shared__ int knS;
  __shared__ int countS;
  int b = blockIdx.x;
  int tid = threadIdx.x;
  const uint64_t* Mb = M + (size_t)b * NPRE * NW;

  for (int w = tid; w < NW; w += 1024) {
    supLo[w] = 0;
    supHi[w] = 0;
    keep[b * NW + w] = 0;  // early-exit leaves tail chunks zeroed
  }
  if (tid == 0) countS = 0;
  __syncthreads();

  for (int c = 0; c < NW; ++c) {
    int ibase = c * 64;
    if (tid < 64) {
      int lane = tid;
      if (lane == 0) knS = 0;
      uint64_t supc = ((uint64_t)supHi[c] << 32) | supLo[c];
      uint64_t validm = (c == NW - 1) ? ((1ull << (NPRE - (NW - 1) * 64)) - 1ull) : ~0ull;
      int pos = ibase + lane;
      uint64_t myrow = (pos < NPRE) ? Mb[(size_t)pos * NW + c] : 0ull;
      bool sval = (pos < NPRE) && (sscore[(size_t)b * NPRE + pos] >= 0.f);
      uint64_t vb = __ballot(sval);
      uint64_t cur = validm & ~supc;
      uint64_t kept = 0;
      while (cur) {
        int i = __ffsll((long long)cur) - 1;
        kept |= (1ull << i);
        cur &= ~(1ull << i);
        uint64_t row = shfl64(myrow, i);
        cur &= ~row;
      }
      if (kept & (1ull << lane)) {
        int pp = atomicAdd(&knS, 1);
        klist[pp] = lane;
      }
      if (lane == 0) {
        keep[b * NW + c] = kept;
        countS += __popcll(kept & vb);
      }
    }
    __syncthreads();  // [A] klist/knS/count visible; sup[c] consumed
    int kn = knS;
    for (int t = tid; t < kn * 128; t += 1024) {
      int ii = t >> 7, w = t & 127;
      if (w > c && w < NW) {
        uint64_t row = Mb[(size_t)(ibase + klist[ii]) * NW + w];
        unsigned int lo = (unsigned int)row;
        unsigned int hi = (unsigned int)(row >> 32);
        if (lo) atomicOr(&supLo[w], lo);
        if (hi) atomicOr(&supHi[w], hi);
      }
    }
    __syncthreads();  // [B] sup updated before next chunk's closure
    if (countS >= 300) break;  // first 300 kept(valid) found; rest irrelevant
  }
}

// ---------------- emit top-300 ----------------
__global__ __launch_bounds__(128) void emit(const uint64_t* __restrict__ keep,
                                            const float* __restrict__ sscore,
                                            const float4* __restrict__ sbox,
                                            float* __restrict__ out) {
  __shared__ int cnt[128];
  __shared__ uint64_t fw[NW];
  int b = blockIdx.x;
  int tid = threadIdx.x;
  for (int i = tid; i < 1200; i += 128) out[b * 1200 + i] = 0.f;
  for (int i = tid; i < 300; i += 128) {
    out[2400 + b * 300 + i] = 0.f;
    out[3000 + b * 300 + i] = 0.f;
  }
  uint64_t w = 0;
  if (tid < NW) {
    uint64_t kw = keep[b * NW + tid];
    while (kw) {
      int j = __ffsll((long long)kw) - 1;
      kw &= kw - 1;
      if (sscore[(size_t)b * NPRE + tid * 64 + j] >= 0.f) w |= (1ull << j);
    }
    fw[tid] = w;
  }
  cnt[tid] = (tid < NW) ? __popcll(w) : 0;
  __syncthreads();
  for (int off = 1; off < 128; off <<= 1) {
    int v = cnt[tid];
    int u = (tid >= off) ? cnt[tid - off] : 0;
    __syncthreads();
    cnt[tid] = v + u;
    __syncthreads();
  }
  if (tid < NW) {
    int base = cnt[tid] - __popcll(fw[tid]);
    uint64_t ww = fw[tid];
    while (ww) {
      int j = __ffsll((long long)ww) - 1;
      ww &= ww - 1;
      if (base < 300) {
        int p = tid * 64 + j;
        float4 bx = sbox[(size_t)b * NPRE + p];
        float* ob = out + b * 1200 + base * 4;
        ob[0] = bx.x; ob[1] = bx.y; ob[2] = bx.z; ob[3] = bx.w;
        out[2400 + b * 300 + base] = sscore[(size_t)b * NPRE + p];
        out[3000 + b * 300 + base] = 1.0f;
      }
      ++base;
    }
  }
}

// ---------------- launch ----------------
extern "C" void kernel_launch(void* const* d_in, const int* in_sizes, int n_in,
                              void* d_out, int out_size, void* d_ws, size_t ws_size,
                              hipStream_t stream) {
  const float* x       = (const float*)d_in[0];
  const float* conv1_w = (const float*)d_in[1];
  const float* conv1_b = (const float*)d_in[2];
  const float* obj_w   = (const float*)d_in[3];
  const float* obj_b   = (const float*)d_in[4];
  const float* loc_w   = (const float*)d_in[5];
  const float* loc_b   = (const float*)d_in[6];
  const float* anch    = (const float*)d_in[7];
  const int*   img_h   = (const int*)d_in[8];
  const int*   img_w   = (const int*)d_in[9];

  char* base = (char*)d_ws;
  float*    wt     = (float*)(base + 0);            // 2304*512*4 = 4,718,592
  float*    h      = (float*)(base + 4718592);      // 2*2500*512*4 = 10,240,000
  uint64_t* M      = (uint64_t*)(base + 4718592);   // alias h (9,024,000 <= 10,240,000)
  float*    scores = (float*)(base + 14958592);     // 180,000
  float4*   boxes  = (float4*)(base + 15138592);    // 720,000
  float*    sscore = (float*)(base + 15858592);     // 48,000
  float4*   sbox   = (float4*)(base + 15906592);    // 192,000
  uint64_t* keep   = (uint64_t*)(base + 16098592);  // 1,504
  float*    xp     = (float*)(base + 16100096);     // 2*256*2704*4 = 5,537,792 -> 21.6MB total

  hipLaunchKernelGGL(pad_x, dim3((2 * 256 * XPAD + 255) / 256), dim3(256), 0, stream, x, xp);
  hipLaunchKernelGGL(transpose_w, dim3(72, 16), dim3(256), 0, stream, conv1_w, wt);
  hipLaunchKernelGGL(conv1_gemm, dim3(40, 8, 2), dim3(256), 0, stream, xp, wt, conv1_b, h);
  hipLaunchKernelGGL(heads, dim3(5000), dim3(64), 0, stream, h, obj_w, obj_b, loc_w, loc_b,
                     anch, img_h, img_w, scores, boxes);
  hipLaunchKernelGGL(topk_sort, dim3(2), dim3(1024), 0, stream, scores, boxes, sscore, sbox);
  hipLaunchKernelGGL(iou_mat, dim3(NW, 24, 2), dim3(256), 0, stream, sbox, M);
  hipLaunchKernelGGL(nms_scan, dim3(2), dim3(1024), 0, stream, M, sscore, keep);
  hipLaunchKernelGGL(emit, dim3(2), dim3(128), 0, stream, keep, sscore, sbox, (float*)d_out);
}

// Round 7
// 523.091 us; speedup vs baseline: 1.3515x; 1.3515x over previous
//
#include <hip/hip_runtime.h>
#include <stdint.h>

// ---------------- constants ----------------
#define NPOS 2500      // 50*50
#define NANCH 22500    // NPOS*9
#define NPRE 6000
#define NW 94          // ceil(6000/64)
#define XPAD 2704      // 52*52 padded plane
#define NSLOT 94       // ceil(NPRE/64) radix slots

// async global->LDS DMA (gfx950). dst is wave-uniform base + lane*size.
__device__ __forceinline__ void gl_lds4(const float* g, float* l) {
  __builtin_amdgcn_global_load_lds((const __attribute__((address_space(1))) void*)g,
                                   (__attribute__((address_space(3))) void*)l, 4, 0, 0);
}
__device__ __forceinline__ void gl_lds16(const float* g, float* l) {
  __builtin_amdgcn_global_load_lds((const __attribute__((address_space(1))) void*)g,
                                   (__attribute__((address_space(3))) void*)l, 16, 0, 0);
}

// ---------------- zero-pad x: [b][ic][50][50] -> [b][ic][52][52] ----------------
__global__ __launch_bounds__(256) void pad_x(const float* __restrict__ x,
                                             float* __restrict__ xp) {
  int t = blockIdx.x * 256 + threadIdx.x;
  if (t >= 2 * 256 * XPAD) return;
  int c = t / XPAD;        // b*256 + ic
  int r = t % XPAD;
  int yy = r / 52, xx = r % 52;
  float v = 0.f;
  if (yy >= 1 && yy <= 50 && xx >= 1 && xx <= 50)
    v = x[(size_t)c * NPOS + (yy - 1) * 50 + (xx - 1)];
  xp[t] = v;
}

// ---------------- weight transpose: w[oc][ic][3][3] -> wt[(tap*256+ic)][oc] ----------------
__global__ __launch_bounds__(256) void transpose_w(const float* __restrict__ w,
                                                   float* __restrict__ wt) {
  __shared__ float tile[32][33];
  int k0 = blockIdx.x * 32;   // k' = ic*9 + tap, 0..2303
  int o0 = blockIdx.y * 32;
  int tx = threadIdx.x & 31;
  int ty = threadIdx.x >> 5;  // 0..7
#pragma unroll
  for (int i = 0; i < 4; ++i) {
    int oc = o0 + ty + i * 8;
    int kp = k0 + tx;
    tile[ty + i * 8][tx] = w[(size_t)oc * 2304 + kp];
  }
  __syncthreads();
#pragma unroll
  for (int i = 0; i < 4; ++i) {
    int kp = k0 + ty + i * 8;
    int ic = kp / 9, tap = kp % 9;
    wt[((size_t)tap * 256 + ic) * 512 + (o0 + tx)] = tile[tx][ty + i * 8];
  }
}

// ---------------- conv1 3x3 SAME + bias + relu, output NHWC h[b][p][oc] ----------------
// R2's 64x64 tile / tap-outer ic-inner K-order (bitwise-identical h), staging via
// global_load_lds DMA from zero-padded xp. (R5: 253 -> ~180us, left top-5.)
__global__ __launch_bounds__(256) void conv1_gemm(const float* __restrict__ xp,
                                                  const float* __restrict__ wt,
                                                  const float* __restrict__ bias,
                                                  float* __restrict__ h) {
  __shared__ __align__(16) float As[32][64];
  __shared__ __align__(16) float Bs[32][64];
  int b = blockIdx.z;
  int m0 = blockIdx.x * 64;
  int oc0 = blockIdx.y * 64;
  int tid = threadIdx.x;
  int lane = tid & 63;
  int wv = tid >> 6;       // wave 0..3
  int tn = tid & 15, tm = tid >> 4;
  float acc[4][4] = {};

  int p = m0 + lane;
  int pc = p < NPOS ? p : (NPOS - 1);
  int py = pc / 50, px = pc % 50;
  const float* gA0 = xp + (size_t)b * 256 * XPAD + py * 52 + px + 53;
  int brow = lane >> 4, bcol4 = (lane & 15) * 4;

  for (int tap = 0; tap < 9; ++tap) {
    int ky = tap / 3 - 1, kx = tap % 3 - 1;
    int koff = ky * 52 + kx;
    for (int icc = 0; icc < 8; ++icc) {
      int ic0 = icc * 32;
      __syncthreads();  // LDS consumed by previous chunk's compute
#pragma unroll
      for (int j = 0; j < 8; ++j) {
        int kk = wv * 8 + j;
        gl_lds4(gA0 + (size_t)(ic0 + kk) * XPAD + koff, &As[kk][0]);
      }
#pragma unroll
      for (int q = 0; q < 2; ++q) {
        int r0 = wv * 8 + q * 4;
        gl_lds16(wt + ((size_t)tap * 256 + ic0 + r0 + brow) * 512 + oc0 + bcol4,
                 &Bs[r0][0]);
      }
      __syncthreads();  // drains vmcnt -> DMAs complete
#pragma unroll
      for (int kk = 0; kk < 32; ++kk) {
        float4 av = *(const float4*)&As[kk][tm * 4];
        float4 bv = *(const float4*)&Bs[kk][tn * 4];
        float am[4] = {av.x, av.y, av.z, av.w};
        float bn[4] = {bv.x, bv.y, bv.z, bv.w};
#pragma unroll
        for (int i = 0; i < 4; ++i)
#pragma unroll
          for (int j = 0; j < 4; ++j) acc[i][j] = fmaf(am[i], bn[j], acc[i][j]);
      }
    }
  }
#pragma unroll
  for (int i = 0; i < 4; ++i) {
    int pp = m0 + tm * 4 + i;
    if (pp < NPOS) {
      float4 v;
      float* vp = (float*)&v;
#pragma unroll
      for (int j = 0; j < 4; ++j) {
        int oc = oc0 + tn * 4 + j;
        vp[j] = fmaxf(acc[i][j] + bias[oc], 0.f);
      }
      *(float4*)&h[((size_t)b * NPOS + pp) * 512 + oc0 + tn * 4] = v;
    }
  }
}

// ---------------- heads: 1x1 convs + softmax + decode + valid ----------------
__global__ __launch_bounds__(64) void heads(const float* __restrict__ h,
                                            const float* __restrict__ objw,
                                            const float* __restrict__ objb,
                                            const float* __restrict__ locw,
                                            const float* __restrict__ locb,
                                            const float* __restrict__ anch,
                                            const int* __restrict__ imgh,
                                            const int* __restrict__ imgw,
                                            float* __restrict__ scores,
                                            float4* __restrict__ boxes) {
  __shared__ float hv[512];
  __shared__ float outs[64];
  int blk = blockIdx.x;
  int b = blk / NPOS, p = blk % NPOS;
  int lane = threadIdx.x;
  const float4* hp4 = (const float4*)(h + ((size_t)b * NPOS + p) * 512);
  float4* hv4 = (float4*)hv;
  hv4[lane] = hp4[lane];
  hv4[lane + 64] = hp4[lane + 64];
  __syncthreads();
  if (lane < 54) {
    const float* wrow;
    float acc;
    if (lane < 18) { wrow = objw + (size_t)lane * 512; acc = objb[lane]; }
    else           { wrow = locw + (size_t)(lane - 18) * 512; acc = locb[lane - 18]; }
    const float4* w4 = (const float4*)wrow;
#pragma unroll 4
    for (int k = 0; k < 128; ++k) {
      float4 wv = w4[k], hh = hv4[k];
      acc = fmaf(wv.x, hh.x, acc);
      acc = fmaf(wv.y, hh.y, acc);
      acc = fmaf(wv.z, hh.z, acc);
      acc = fmaf(wv.w, hh.w, acc);
    }
    outs[lane] = acc;
  }
  __syncthreads();
  if (lane < 9) {
    float l0 = outs[2 * lane], l1 = outs[2 * lane + 1];
    float mx = fmaxf(l0, l1);
    float e0 = expf(l0 - mx);
    float e1 = expf(l1 - mx);
    float s = e1 / (e0 + e1);
    float d0 = outs[18 + 4 * lane + 0];
    float d1 = outs[18 + 4 * lane + 1];
    float d2 = outs[18 + 4 * lane + 2];
    float d3 = outs[18 + 4 * lane + 3];
    int ai = p * 9 + lane;
    float4 A = ((const float4*)anch)[ai];
    float aw = A.z - A.x, ah = A.w - A.y;
    float acx = A.x + 0.5f * aw, acy = A.y + 0.5f * ah;
    float cx = acx + d0 * aw, cy = acy + d1 * ah;
    float w = aw * expf(d2), hh = ah * expf(d3);
    float W = (float)imgw[0], H = (float)imgh[0];
    float x1 = fminf(fmaxf(cx - 0.5f * w, 0.f), W);
    float y1 = fminf(fmaxf(cy - 0.5f * hh, 0.f), H);
    float x2 = fminf(fmaxf(cx + 0.5f * w, 0.f), W);
    float y2 = fminf(fmaxf(cy + 0.5f * hh, 0.f), H);
    bool valid = (x2 - x1 >= 16.f) && (y2 - y1 >= 16.f);
    scores[(size_t)b * NANCH + ai] = valid ? s : -1.f;
    boxes[(size_t)b * NANCH + ai] = make_float4(x1, y1, x2, y2);
  }
}

// ---------------- top-6000 select + stable radix sort (one block per batch) ----------------
__device__ inline unsigned int mono_of(float f) {
  unsigned int u = __float_as_uint(f);
  return (u & 0x80000000u) ? ~u : (u | 0x80000000u);
}

// R6 lesson: wave-aggregated hist_add REGRESSED (+67us) — serial ballot chains cost
// more than the ~9us of LDS atomic conflicts they remove. Plain atomics restored.
// R5/R6 lesson: the 8192-bitonic (91 steps, 182 barriers, single CU) was ~150us of
// the 201/268 — replaced by 6-pass 6-bit stable LSD radix on n=6000 (~35 barriers).
__global__ __launch_bounds__(1024) void topk_sort(const float* __restrict__ scores,
                                                  const float4* __restrict__ boxes,
                                                  float* __restrict__ sscore,
                                                  float4* __restrict__ sbox) {
  int b = blockIdx.x;
  const float* sc = scores + (size_t)b * NANCH;
  __shared__ unsigned int hist[4096];
  __shared__ unsigned int part[1024];
  __shared__ unsigned short pidA[6016];
  __shared__ unsigned short pidB[6016];
  __shared__ unsigned short table[6144];   // 64 digits x 94 slots (padded)
  __shared__ int res[8];
  int tid = threadIdx.x;
  int lane = tid & 63;
  int wv = tid >> 6;

  // ---------- phase 1: top-12-bit histogram ----------
  for (int i = tid; i < 4096; i += 1024) hist[i] = 0;
  __syncthreads();
  for (int i = tid; i < NANCH; i += 1024) atomicAdd(&hist[mono_of(sc[i]) >> 20], 1u);
  __syncthreads();
  {
    unsigned int h0 = hist[4 * tid], h1 = hist[4 * tid + 1];
    unsigned int h2 = hist[4 * tid + 2], h3 = hist[4 * tid + 3];
    part[tid] = h0 + h1 + h2 + h3;
    __syncthreads();
    for (int off = 1; off < 1024; off <<= 1) {
      unsigned int v = part[tid];
      unsigned int u = (tid + off < 1024) ? part[tid + off] : 0;
      __syncthreads();
      part[tid] = v + u;
      __syncthreads();
    }
    unsigned int c = (tid < 1023) ? part[tid + 1] : 0;  // strict suffix over groups
    const int need = NPRE;
    if (c < (unsigned)need && c + h3 >= (unsigned)need) { res[0] = 4 * tid + 3; res[1] = (int)c; }
    c += h3;
    if (c < (unsigned)need && c + h2 >= (unsigned)need) { res[0] = 4 * tid + 2; res[1] = (int)c; }
    c += h2;
    if (c < (unsigned)need && c + h1 >= (unsigned)need) { res[0] = 4 * tid + 1; res[1] = (int)c; }
    c += h1;
    if (c < (unsigned)need && c + h0 >= (unsigned)need) { res[0] = 4 * tid + 0; res[1] = (int)c; }
  }
  __syncthreads();
  int t1 = res[0], a1 = res[1];
  __syncthreads();

  // ---------- phase 2: middle-12 bits within bin t1 ----------
  for (int i = tid; i < 4096; i += 1024) hist[i] = 0;
  __syncthreads();
  for (int i = tid; i < NANCH; i += 1024) {
    unsigned int m = mono_of(sc[i]);
    if ((int)(m >> 20) == t1) atomicAdd(&hist[(m >> 8) & 0xFFF], 1u);
  }
  __syncthreads();
  {
    unsigned int h0 = hist[4 * tid], h1 = hist[4 * tid + 1];
    unsigned int h2 = hist[4 * tid + 2], h3 = hist[4 * tid + 3];
    part[tid] = h0 + h1 + h2 + h3;
    __syncthreads();
    for (int off = 1; off < 1024; off <<= 1) {
      unsigned int v = part[tid];
      unsigned int u = (tid + off < 1024) ? part[tid + off] : 0;
      __syncthreads();
      part[tid] = v + u;
      __syncthreads();
    }
    unsigned int c = (tid < 1023) ? part[tid + 1] : 0;
    const unsigned int need = (unsigned)(NPRE - a1);
    if (c < need && c + h3 >= need) { res[2] = 4 * tid + 3; res[3] = (int)c; }
    c += h3;
    if (c < need && c + h2 >= need) { res[2] = 4 * tid + 2; res[3] = (int)c; }
    c += h2;
    if (c < need && c + h1 >= need) { res[2] = 4 * tid + 1; res[3] = (int)c; }
    c += h1;
    if (c < need && c + h0 >= need) { res[2] = 4 * tid + 0; res[3] = (int)c; }
  }
  __syncthreads();
  int t2 = res[2], a2 = res[3];
  __syncthreads();

  // ---------- phase 3: low-8 bits within (t1,t2) ----------
  for (int i = tid; i < 256; i += 1024) hist[i] = 0;
  __syncthreads();
  unsigned int top24 = ((unsigned int)t1 << 12) | (unsigned int)t2;
  for (int i = tid; i < NANCH; i += 1024) {
    unsigned int m = mono_of(sc[i]);
    if ((m >> 8) == top24) atomicAdd(&hist[m & 0xFF], 1u);
  }
  __syncthreads();
  {
    unsigned int hb = (tid < 256) ? hist[tid] : 0;
    part[tid] = hb;
    __syncthreads();
    for (int off = 1; off < 1024; off <<= 1) {
      unsigned int v = part[tid];
      unsigned int u = (tid + off < 1024) ? part[tid + off] : 0;
      __syncthreads();
      part[tid] = v + u;
      __syncthreads();
    }
    if (tid < 256) {
      unsigned int c = part[tid + 1];
      const unsigned int need = (unsigned)(NPRE - a1 - a2);
      if (c < need && c + hb >= need) {
        res[4] = tid;
        res[6] = (int)(need - c);                         // ties_needed
        res[7] = (hb == need - c) ? NANCH : -1;           // idx_cut or TBD
      }
    }
  }
  __syncthreads();
  int t3 = res[4];
  unsigned int T = (top24 << 8) | (unsigned int)t3;
  int ties_needed = res[6];
  int idx_cut = res[7];
  __syncthreads();

  // ---------- phase 4 (rare): tie resolution by smallest index ----------
  if (idx_cut < 0) {
    for (int i = tid; i < 704; i += 1024) hist[i] = 0;
    __syncthreads();
    for (int i = tid; i < NANCH; i += 1024)
      if (mono_of(sc[i]) == T) atomicAdd(&hist[i >> 5], 1u);
    __syncthreads();
    if (tid == 0) {
      int c = 0, cut = NANCH;
      for (int bin = 0; bin < 704; ++bin) {
        int hc = (int)hist[bin];
        if (c + hc >= ties_needed) {
          int c2 = c;
          for (int idx = bin * 32; idx < bin * 32 + 32; ++idx) {
            if (idx < NANCH && mono_of(sc[idx]) == T) {
              ++c2;
              if (c2 == ties_needed) { cut = idx; break; }
            }
          }
          break;
        }
        c += hc;
      }
      res[7] = cut;
    }
    __syncthreads();
    idx_cut = res[7];
    __syncthreads();
  }

  // ---------- phase 5: deterministic idx-order compact (blocked ranges + scan) ----------
  // radix stability requires pidA in ascending anchor-idx order.
  int base0 = tid * 22;  // 1024*22 = 22528 >= NANCH
  unsigned int selm = 0;
  int cnt = 0;
  for (int k = 0; k < 22; ++k) {
    int i = base0 + k;
    if (i < NANCH) {
      unsigned int m = mono_of(sc[i]);
      if (m > T || (m == T && i <= idx_cut)) { selm |= 1u << k; ++cnt; }
    }
  }
  {
    int inc = cnt;
#pragma unroll
    for (int d = 1; d < 64; d <<= 1) {
      int u = __shfl_up(inc, d, 64);
      if (lane >= d) inc += u;
    }
    if (lane == 63) part[wv] = (unsigned int)inc;
    __syncthreads();
    if (tid < 16) {
      int v = (int)part[tid];
      int inc2 = v;
#pragma unroll
      for (int d = 1; d < 16; d <<= 1) {
        int u = __shfl_up(inc2, d, 16);
        if (tid >= d) inc2 += u;
      }
      part[tid] = (unsigned int)(inc2 - v);  // exclusive wave base
    }
    __syncthreads();
    int pos = (int)part[wv] + (inc - cnt);
    for (int k = 0; k < 22; ++k)
      if ((selm >> k) & 1u) pidA[pos++] = (unsigned short)(base0 + k);
  }
  __syncthreads();

  // ---------- phase 6: 6-pass 6-bit stable LSD radix, key = ~mono (asc) ----------
  unsigned short* src = pidA;
  unsigned short* dst = pidB;
  for (int pass = 0; pass < 6; ++pass) {
    int shift = pass * 6;
    for (int i = tid; i < 6144; i += 1024) table[i] = 0;
    __syncthreads();
    int dig[6], irk[6], pidr[6];
#pragma unroll
    for (int k = 0; k < 6; ++k) {
      dig[k] = 0; irk[k] = 0; pidr[k] = 0;
      int s = wv + 16 * k;          // wave-uniform
      if (s < NSLOT) {
        int e = s * 64 + lane;
        bool act = e < NPRE;
        int pid = act ? (int)src[e] : 0;
        unsigned int key = act ? ~mono_of(sc[pid]) : 0u;
        int d = (int)((key >> shift) & 63u);
        uint64_t peers = __ballot(act);
#pragma unroll
        for (int bb = 0; bb < 6; ++bb) {
          uint64_t bl = __ballot(((d >> bb) & 1) != 0);
          peers &= ((d >> bb) & 1) ? bl : ~bl;
        }
        if (act) {
          dig[k] = d;
          pidr[k] = pid;
          irk[k] = (int)__popcll(peers & ((1ull << lane) - 1ull));
          int leader = __ffsll((long long)peers) - 1;
          if (lane == leader)
            table[d * NSLOT + s] = (unsigned short)__popcll(peers);
        }
      }
    }
    __syncthreads();
    // exclusive scan over table[0..6143] (digit-major, slot-minor)
    {
      int t6 = tid * 6;
      int v0 = table[t6], v1 = table[t6 + 1], v2 = table[t6 + 2];
      int v3 = table[t6 + 3], v4 = table[t6 + 4], v5 = table[t6 + 5];
      int lsum = v0 + v1 + v2 + v3 + v4 + v5;
      int inc = lsum;
#pragma unroll
      for (int d = 1; d < 64; d <<= 1) {
        int u = __shfl_up(inc, d, 64);
        if (lane >= d) inc += u;
      }
      if (lane == 63) part[wv] = (unsigned int)inc;
      __syncthreads();
      if (tid < 16) {
        int v = (int)part[tid];
        int inc2 = v;
#pragma unroll
        for (int d = 1; d < 16; d <<= 1) {
          int u = __shfl_up(inc2, d, 16);
          if (tid >= d) inc2 += u;
        }
        part[tid] = (unsigned int)(inc2 - v);
      }
      __syncthreads();
      int run = (int)part[wv] + (inc - lsum);
      table[t6] = (unsigned short)run; run += v0;
      table[t6 + 1] = (unsigned short)run; run += v1;
      table[t6 + 2] = (unsigned short)run; run += v2;
      table[t6 + 3] = (unsigned short)run; run += v3;
      table[t6 + 4] = (unsigned short)run; run += v4;
      table[t6 + 5] = (unsigned short)run;
    }
    __syncthreads();
    // scatter (stable): pos = base(digit,slot) + intra-slot rank
#pragma unroll
    for (int k = 0; k < 6; ++k) {
      int s = wv + 16 * k;
      if (s < NSLOT) {
        int e = s * 64 + lane;
        if (e < NPRE) {
          int pos = (int)table[dig[k] * NSLOT + s] + irk[k];
          dst[pos] = (unsigned short)pidr[k];
        }
      }
    }
    __syncthreads();
    unsigned short* tmp = src; src = dst; dst = tmp;
  }
  // 6 passes -> result back in pidA (== src)

  // ---------- phase 7: gather sorted scores/boxes ----------
  for (int r = tid; r < NPRE; r += 1024) {
    int idx = (int)src[r];
    sscore[(size_t)b * NPRE + r] = sc[idx];
    sbox[(size_t)b * NPRE + r] = boxes[(size_t)b * NANCH + idx];
  }
}

// ---------------- IoU suppression bitmask ----------------
__global__ __launch_bounds__(256) void iou_mat(const float4* __restrict__ sbox,
                                               uint64_t* __restrict__ M) {
  __shared__ float4 bi[64];
  __shared__ float4 bj[256];
  int b = blockIdx.z;
  int it = blockIdx.x;  // 94 tiles of 64 i
  int jt = blockIdx.y;  // 24 tiles of 4 words
  int tid = threadIdx.x;
  if (tid < 64) {
    int i = it * 64 + tid;
    bi[tid] = (i < NPRE) ? sbox[(size_t)b * NPRE + i] : make_float4(0, 0, 0, 0);
  }
  {
    int j = jt * 256 + tid;
    bj[tid] = (j < NPRE) ? sbox[(size_t)b * NPRE + j] : make_float4(0, 0, 0, 0);
  }
  __syncthreads();
  int li = tid & 63, wq = tid >> 6;
  int i = it * 64 + li;
  int w = jt * 4 + wq;
  if (i < NPRE && w < NW) {
    float4 A = bi[li];
    float areaA = (A.z - A.x) * (A.w - A.y);
    uint64_t bits = 0;
#pragma unroll 8
    for (int jj = 0; jj < 64; ++jj) {
      int j = w * 64 + jj;
      float4 Bx = bj[wq * 64 + jj];
      float ix1 = fmaxf(A.x, Bx.x), iy1 = fmaxf(A.y, Bx.y);
      float ix2 = fminf(A.z, Bx.z), iy2 = fminf(A.w, Bx.w);
      float inter = fmaxf(ix2 - ix1, 0.f) * fmaxf(iy2 - iy1, 0.f);
      float areaB = (Bx.z - Bx.x) * (Bx.w - Bx.y);
      float iou = inter / (areaA + areaB - inter);
      if ((j > i) && (j < NPRE) && (iou > 0.7f)) bits |= (1ull << jj);
    }
    M[((size_t)b * NPRE + i) * NW + w] = bits;
  }
}

// ---------------- NMS scan: wave0 serial closure + block-parallel OR + early exit ----------------
__device__ inline uint64_t shfl64(uint64_t v, int src) {
  int lo = __shfl((int)(unsigned int)(v & 0xFFFFFFFFull), src, 64);
  int hi = __shfl((int)(unsigned int)(v >> 32), src, 64);
  return ((uint64_t)(unsigned int)hi << 32) | (unsigned int)lo;
}

__global__ __launch_bounds__(1024) void nms_scan(const uint64_t* __restrict__ M,
                                                 const float* __restrict__ sscore,
                                                 uint64_t* __restrict__ keep) {
  __shared__ unsigned int supLo[NW], supHi[NW];
  __shared__ int klist[64];
  __shared__ int knS;
  __shared__ int countS;
  int b = blockIdx.x;
  int tid = threadIdx.x;
  const uint64_t* Mb = M + (size_t)b * NPRE * NW;

  for (int w = tid; w < NW; w += 1024) {
    supLo[w] = 0;
    supHi[w] = 0;
    keep[b * NW + w] = 0;  // early-exit leaves tail chunks zeroed
  }
  if (tid == 0) countS = 0;
  __syncthreads();

  for (int c = 0; c < NW; ++c) {
    int ibase = c * 64;
    if (tid < 64) {
      int lane = tid;
      if (lane == 0) knS = 0;
      uint64_t supc = ((uint64_t)supHi[c] << 32) | supLo[c];
      uint64_t validm = (c == NW - 1) ? ((1ull << (NPRE - (NW - 1) * 64)) - 1ull) : ~0ull;
      int pos = ibase + lane;
      uint64_t myrow = (pos < NPRE) ? Mb[(size_t)pos * NW + c] : 0ull;
      bool sval = (pos < NPRE) && (sscore[(size_t)b * NPRE + pos] >= 0.f);
      uint64_t vb = __ballot(sval);
      uint64_t cur = validm & ~supc;
      uint64_t kept = 0;
      while (cur) {
        int i = __ffsll((long long)cur) - 1;
        kept |= (1ull << i);
        cur &= ~(1ull << i);
        uint64_t row = shfl64(myrow, i);
        cur &= ~row;
      }
      if (kept & (1ull << lane)) {
        int pp = atomicAdd(&knS, 1);
        klist[pp] = lane;
      }
      if (lane == 0) {
        keep[b * NW + c] = kept;
        countS += __popcll(kept & vb);
      }
    }
    __syncthreads();  // [A] klist/knS/count visible; sup[c] consumed
    int kn = knS;
    for (int t = tid; t < kn * 128; t += 1024) {
      int ii = t >> 7, w = t & 127;
      if (w > c && w < NW) {
        uint64_t row = Mb[(size_t)(ibase + klist[ii]) * NW + w];
        unsigned int lo = (unsigned int)row;
        unsigned int hi = (unsigned int)(row >> 32);
        if (lo) atomicOr(&supLo[w], lo);
        if (hi) atomicOr(&supHi[w], hi);
      }
    }
    __syncthreads();  // [B] sup updated before next chunk's closure
    if (countS >= 300) break;  // first 300 kept(valid) found; rest irrelevant
  }
}

// ---------------- emit top-300 ----------------
__global__ __launch_bounds__(128) void emit(const uint64_t* __restrict__ keep,
                                            const float* __restrict__ sscore,
                                            const float4* __restrict__ sbox,
                                            float* __restrict__ out) {
  __shared__ int cnt[128];
  __shared__ uint64_t fw[NW];
  int b = blockIdx.x;
  int tid = threadIdx.x;
  for (int i = tid; i < 1200; i += 128) out[b * 1200 + i] = 0.f;
  for (int i = tid; i < 300; i += 128) {
    out[2400 + b * 300 + i] = 0.f;
    out[3000 + b * 300 + i] = 0.f;
  }
  uint64_t w = 0;
  if (tid < NW) {
    uint64_t kw = keep[b * NW + tid];
    while (kw) {
      int j = __ffsll((long long)kw) - 1;
      kw &= kw - 1;
      if (sscore[(size_t)b * NPRE + tid * 64 + j] >= 0.f) w |= (1ull << j);
    }
    fw[tid] = w;
  }
  cnt[tid] = (tid < NW) ? __popcll(w) : 0;
  __syncthreads();
  for (int off = 1; off < 128; off <<= 1) {
    int v = cnt[tid];
    int u = (tid >= off) ? cnt[tid - off] : 0;
    __syncthreads();
    cnt[tid] = v + u;
    __syncthreads();
  }
  if (tid < NW) {
    int base = cnt[tid] - __popcll(fw[tid]);
    uint64_t ww = fw[tid];
    while (ww) {
      int j = __ffsll((long long)ww) - 1;
      ww &= ww - 1;
      if (base < 300) {
        int p = tid * 64 + j;
        float4 bx = sbox[(size_t)b * NPRE + p];
        float* ob = out + b * 1200 + base * 4;
        ob[0] = bx.x; ob[1] = bx.y; ob[2] = bx.z; ob[3] = bx.w;
        out[2400 + b * 300 + base] = sscore[(size_t)b * NPRE + p];
        out[3000 + b * 300 + base] = 1.0f;
      }
      ++base;
    }
  }
}

// ---------------- launch ----------------
extern "C" void kernel_launch(void* const* d_in, const int* in_sizes, int n_in,
                              void* d_out, int out_size, void* d_ws, size_t ws_size,
                              hipStream_t stream) {
  const float* x       = (const float*)d_in[0];
  const float* conv1_w = (const float*)d_in[1];
  const float* conv1_b = (const float*)d_in[2];
  const float* obj_w   = (const float*)d_in[3];
  const float* obj_b   = (const float*)d_in[4];
  const float* loc_w   = (const float*)d_in[5];
  const float* loc_b   = (const float*)d_in[6];
  const float* anch    = (const float*)d_in[7];
  const int*   img_h   = (const int*)d_in[8];
  const int*   img_w   = (const int*)d_in[9];

  char* base = (char*)d_ws;
  float*    wt     = (float*)(base + 0);            // 2304*512*4 = 4,718,592
  float*    h      = (float*)(base + 4718592);      // 2*2500*512*4 = 10,240,000
  uint64_t* M      = (uint64_t*)(base + 4718592);   // alias h (9,024,000 <= 10,240,000)
  float*    scores = (float*)(base + 14958592);     // 180,000
  float4*   boxes  = (float4*)(base + 15138592);    // 720,000
  float*    sscore = (float*)(base + 15858592);     // 48,000
  float4*   sbox   = (float4*)(base + 15906592);    // 192,000
  uint64_t* keep   = (uint64_t*)(base + 16098592);  // 1,504
  float*    xp     = (float*)(base + 16100096);     // 2*256*2704*4 = 5,537,792 -> 21.6MB total

  hipLaunchKernelGGL(pad_x, dim3((2 * 256 * XPAD + 255) / 256), dim3(256), 0, stream, x, xp);
  hipLaunchKernelGGL(transpose_w, dim3(72, 16), dim3(256), 0, stream, conv1_w, wt);
  hipLaunchKernelGGL(conv1_gemm, dim3(40, 8, 2), dim3(256), 0, stream, xp, wt, conv1_b, h);
  hipLaunchKernelGGL(heads, dim3(5000), dim3(64), 0, stream, h, obj_w, obj_b, loc_w, loc_b,
                     anch, img_h, img_w, scores, boxes);
  hipLaunchKernelGGL(topk_sort, dim3(2), dim3(1024), 0, stream, scores, boxes, sscore, sbox);
  hipLaunchKernelGGL(iou_mat, dim3(NW, 24, 2), dim3(256), 0, stream, sbox, M);
  hipLaunchKernelGGL(nms_scan, dim3(2), dim3(1024), 0, stream, M, sscore, keep);
  hipLaunchKernelGGL(emit, dim3(2), dim3(128), 0, stream, keep, sscore, sbox, (float*)d_out);
}